// Round 2
// baseline (679.974 us; speedup 1.0000x reference)
//
#include <hip/hip_runtime.h>
#include <math.h>
#include <float.h>

#define BATCH 8
#define HIGH  256
#define LOWR  64
#define NN    4096          // LOWR*LOWR
#define HIDC  16
#define C1    64

// workspace layout (floats)
#define OFF_XL   0
#define OFF_H1   (OFF_XL  + BATCH*NN)            // 32768
#define OFF_H    (OFF_H1  + BATCH*C1*NN)         // node-major [B*N][16]
#define OFF_SQ   (OFF_H   + BATCH*NN*HIDC)
#define OFF_XP   (OFF_SQ  + BATCH*NN)
#define OFF_ASR  (OFF_XP  + BATCH*NN*HIDC)
#define OFF_ADT  (OFF_ASR + BATCH*NN*4)
#define OFF_P    (OFF_ADT + BATCH*NN*4)
#define OFF_OL   (OFF_P   + BATCH*NN*HIDC)

// ---------------- bilinear downsample 256 -> 64 (antialiased triangle) -------
__global__ void k_down(const float* __restrict__ x, float* __restrict__ xl) {
    int t = blockIdx.x * 128 + threadIdx.x;
    if (t >= BATCH * NN) return;
    int b = t >> 12, oy = (t >> 6) & 63, ox = t & 63;
    const float* xb = x + b * HIGH * HIGH;
    float cy = 4.f * oy + 1.5f, cx = 4.f * ox + 1.5f;
    float wy[8], wx[8], sy = 0.f, sx = 0.f;
#pragma unroll
    for (int k = 0; k < 8; k++) {
        int iy = 4 * oy - 2 + k;
        float w = 1.f - fabsf((float)iy - cy) * 0.25f;
        if (iy < 0 || iy >= HIGH) w = 0.f;
        wy[k] = w; sy += w;
        int ix = 4 * ox - 2 + k;
        float v = 1.f - fabsf((float)ix - cx) * 0.25f;
        if (ix < 0 || ix >= HIGH) v = 0.f;
        wx[k] = v; sx += v;
    }
    float acc = 0.f;
#pragma unroll
    for (int ky = 0; ky < 8; ky++) {
        if (wy[ky] == 0.f) continue;
        int iy = 4 * oy - 2 + ky;
        float rowacc = 0.f;
#pragma unroll
        for (int kx = 0; kx < 8; kx++) {
            if (wx[kx] == 0.f) continue;
            int ix = 4 * ox - 2 + kx;
            rowacc += wx[kx] * xb[iy * HIGH + ix];
        }
        acc += wy[ky] * rowacc;
    }
    xl[t] = acc / (sy * sx);
}

// ---------------- conv3x3 1->64 + BN + relu ---------------------------------
__global__ void k_conv1(const float* __restrict__ xl, const float* __restrict__ W1,
                        const float* __restrict__ b1, const float* __restrict__ g1,
                        const float* __restrict__ be1, const float* __restrict__ m1,
                        const float* __restrict__ v1, float* __restrict__ h1) {
    int t = blockIdx.x * 256 + threadIdx.x;
    if (t >= BATCH * C1 * NN) return;
    int b = t >> 18, co = (t >> 12) & 63, y = (t >> 6) & 63, x = t & 63;
    const float* src = xl + b * NN;
    const float* w = W1 + co * 9;
    float acc = 0.f;
#pragma unroll
    for (int dy = -1; dy <= 1; dy++) {
        int yy = y + dy; if (yy < 0 || yy >= 64) continue;
#pragma unroll
        for (int dx = -1; dx <= 1; dx++) {
            int xx = x + dx; if (xx < 0 || xx >= 64) continue;
            acc += w[(dy + 1) * 3 + (dx + 1)] * src[yy * 64 + xx];
        }
    }
    acc += b1[co];
    float sc = g1[co] / sqrtf(v1[co] + 1e-5f);
    acc = (acc - m1[co]) * sc + be1[co];
    h1[t] = fmaxf(acc, 0.f);
}

// ------- conv3x3 64->16 + BN + relu, fused: h (node-major), sq, xp, asr, adt -
// weight layout in LDS: [(ci*9+tap)][o] so the 16 o-weights read as 4x b128
// block = 128 threads (2 rows x 64 cols); grid = 8 batches * 32 y-tiles = 256
__launch_bounds__(128)
__global__ void k_conv2(const float* __restrict__ h1, const float* __restrict__ W2,
                        const float* __restrict__ b2, const float* __restrict__ g2,
                        const float* __restrict__ be2, const float* __restrict__ m2,
                        const float* __restrict__ v2, const float* __restrict__ Wg,
                        const float* __restrict__ a_src, const float* __restrict__ a_dst,
                        float* __restrict__ h, float* __restrict__ sq,
                        float* __restrict__ xp, float* __restrict__ asr,
                        float* __restrict__ adt) {
    __shared__ float sW2t[576 * 16];    // [ci*9+tap][o]
    __shared__ float sWg[256];
    __shared__ float sA[32];
    int tid = threadIdx.x;
    for (int k = tid; k < 9216; k += 128) {          // coalesced global read, scatter to LDS
        int o = k / 576, ct = k - o * 576;
        sW2t[ct * 16 + o] = W2[k];
    }
    for (int k = tid; k < 256; k += 128) sWg[k] = Wg[k];
    if (tid < 16) { sA[tid] = a_src[tid]; sA[16 + tid] = a_dst[tid]; }
    __syncthreads();
    int blk = blockIdx.x;                 // 8 batches * 32 y-tiles
    int b = blk >> 5, ytile = blk & 31;
    int ty = tid >> 6, x = tid & 63, y = ytile * 2 + ty;
    float acc[16];
#pragma unroll
    for (int o = 0; o < 16; o++) acc[o] = 0.f;
    const float* hb = h1 + (long)b * C1 * NN;
    for (int ci = 0; ci < 64; ci++) {
        const float* plane = hb + ci * NN;
#pragma unroll
        for (int dy = -1; dy <= 1; dy++) {
            int yy = y + dy; bool oky = (yy >= 0 && yy < 64);
#pragma unroll
            for (int dx = -1; dx <= 1; dx++) {
                int xx = x + dx;
                float v = (oky && xx >= 0 && xx < 64) ? plane[yy * 64 + xx] : 0.f;
                int ct = ci * 9 + (dy + 1) * 3 + (dx + 1);
                const float4* wr = (const float4*)&sW2t[ct * 16];
                float4 w0 = wr[0], w1 = wr[1], w2 = wr[2], w3 = wr[3];
                acc[0] += v * w0.x; acc[1] += v * w0.y; acc[2] += v * w0.z; acc[3] += v * w0.w;
                acc[4] += v * w1.x; acc[5] += v * w1.y; acc[6] += v * w1.z; acc[7] += v * w1.w;
                acc[8] += v * w2.x; acc[9] += v * w2.y; acc[10]+= v * w2.z; acc[11]+= v * w2.w;
                acc[12]+= v * w3.x; acc[13]+= v * w3.y; acc[14]+= v * w3.z; acc[15]+= v * w3.w;
            }
        }
    }
    int n = y * 64 + x;
    long node = (long)b * NN + n;
    float nodev[16], sqv = 0.f;
#pragma unroll
    for (int o = 0; o < 16; o++) {
        float a = acc[o] + b2[o];
        float sc = g2[o] / sqrtf(v2[o] + 1e-5f);
        a = (a - m2[o]) * sc + be2[o];
        a = fmaxf(a, 0.f);
        nodev[o] = a; sqv += a * a;
        h[node * 16 + o] = a;
    }
    sq[node] = sqv;
    float xpv[16];
#pragma unroll
    for (int o = 0; o < 16; o++) {
        float a = 0.f;
#pragma unroll
        for (int c = 0; c < 16; c++) a += sWg[o * 16 + c] * nodev[c];
        xpv[o] = a;
        xp[node * 16 + o] = a;
    }
#pragma unroll
    for (int hh = 0; hh < 4; hh++) {
        float as = 0.f, ad = 0.f;
#pragma unroll
        for (int f = 0; f < 4; f++) {
            as += xpv[hh * 4 + f] * sA[hh * 4 + f];
            ad += xpv[hh * 4 + f] * sA[16 + hh * 4 + f];
        }
        asr[node * 4 + hh] = as;
        adt[node * 4 + hh] = ad;
    }
}

// --------- kNN (K=8, excl self) + GAT(4 heads) + bias + relu -> p -----------
// block = 256 threads = 8 half-wave segments x 32 lanes; each thread owns 4 rows.
// rows/block = 128; grid = 8 batches * 32 = 256 blocks (1/CU).
// score = dot(i,j) - 0.5*|j|^2  (monotone-equivalent to -dist; sqi is per-row const)
#define SEGS 8
#define RPT  4
#define TSTR 20   // tile stride in floats (80 B: 16B-aligned, breaks pow2 banks)
__launch_bounds__(256, 1)
__global__ void k_gat(const float* __restrict__ h, const float* __restrict__ sq,
                      const float* __restrict__ xp, const float* __restrict__ asr,
                      const float* __restrict__ adt, const float* __restrict__ bg,
                      float* __restrict__ p) {
    __shared__ float tileN[256 * TSTR];
    __shared__ float sqh[256];
    __shared__ float md[128 * 8 * 9];            // per-(row,seg) top-8 lists, stride 9
    __shared__ unsigned short mi[128 * 8 * 9];
    int tid = threadIdx.x;
    int b = blockIdx.x >> 5;
    int rowbase = (blockIdx.x & 31) * 128;
    int seg = tid >> 5, lane = tid & 31;
    long bN = (long)b * NN;

    float ni[RPT][16];
    int irow[RPT];
#pragma unroll
    for (int rr = 0; rr < RPT; rr++) {
        irow[rr] = rowbase + lane + rr * 32;
        const float4* src = (const float4*)&h[(bN + irow[rr]) * 16];
        float4 v0 = src[0], v1 = src[1], v2 = src[2], v3 = src[3];
        ni[rr][0]=v0.x; ni[rr][1]=v0.y; ni[rr][2]=v0.z; ni[rr][3]=v0.w;
        ni[rr][4]=v1.x; ni[rr][5]=v1.y; ni[rr][6]=v1.z; ni[rr][7]=v1.w;
        ni[rr][8]=v2.x; ni[rr][9]=v2.y; ni[rr][10]=v2.z; ni[rr][11]=v2.w;
        ni[rr][12]=v3.x; ni[rr][13]=v3.y; ni[rr][14]=v3.z; ni[rr][15]=v3.w;
    }
    float s[RPT][8]; int id[RPT][8];
#pragma unroll
    for (int rr = 0; rr < RPT; rr++)
#pragma unroll
        for (int k = 0; k < 8; k++) { s[rr][k] = -FLT_MAX; id[rr][k] = 65535; }

    for (int tile = 0; tile < 16; tile++) {
        int jbase = tile * 256;
        __syncthreads();
        {   // stage 256 j-nodes; stride-20 floats kills staging bank conflicts
            const float4* src = (const float4*)&h[(bN + jbase + tid) * 16];
            float4 a0 = src[0], a1 = src[1], a2 = src[2], a3 = src[3];
            float4* dst = (float4*)&tileN[tid * TSTR];
            dst[0] = a0; dst[1] = a1; dst[2] = a2; dst[3] = a3;
            sqh[tid] = 0.5f * sq[bN + jbase + tid];
        }
        __syncthreads();
        for (int q = 0; q < 32; q++) {
            int jj = (q << 3) + seg;      // segment-interleaved: one staged tile serves all
            const float4* tn = (const float4*)&tileN[jj * TSTR];
            float4 a0 = tn[0], a1 = tn[1], a2 = tn[2], a3 = tn[3];
            float aj[16] = { a0.x,a0.y,a0.z,a0.w, a1.x,a1.y,a1.z,a1.w,
                             a2.x,a2.y,a2.z,a2.w, a3.x,a3.y,a3.z,a3.w };
            float hs = sqh[jj];
            int j = jbase + jj;
#pragma unroll
            for (int rr = 0; rr < RPT; rr++) {
                float dot = 0.f;
#pragma unroll
                for (int c = 0; c < 16; c++) dot += ni[rr][c] * aj[c];
                float sc = dot - hs;
                if (sc > s[rr][7] && j != irow[rr]) {   // strict >: earliest j kept on tie
                    s[rr][7] = sc; id[rr][7] = j;
#pragma unroll
                    for (int k = 7; k > 0; k--) {
                        if (s[rr][k] > s[rr][k - 1]) {
                            float td = s[rr][k]; s[rr][k] = s[rr][k - 1]; s[rr][k - 1] = td;
                            int tj = id[rr][k]; id[rr][k] = id[rr][k - 1]; id[rr][k - 1] = tj;
                        }
                    }
                }
            }
        }
    }
    // dump per-segment lists (stride 9 -> conflict-light)
#pragma unroll
    for (int rr = 0; rr < RPT; rr++) {
        int row = lane + rr * 32;
        int base = (row * 8 + seg) * 9;
#pragma unroll
        for (int k = 0; k < 8; k++) {
            md[base + k] = s[rr][k];
            mi[base + k] = (unsigned short)id[rr][k];
        }
    }
    __syncthreads();

    if (tid < 128) {
        int i = rowbase + tid;
        // merge 8 lists, lexicographic (score desc, idx asc) == jax top_k tie rule
        float fS[8]; int fI[8];
#pragma unroll
        for (int k = 0; k < 8; k++) { fS[k] = -FLT_MAX; fI[k] = 65535; }
        for (int sg = 0; sg < 8; sg++) {
            int base = (tid * 8 + sg) * 9;
#pragma unroll
            for (int k = 0; k < 8; k++) {
                float d = md[base + k]; int j = (int)mi[base + k];
                bool bt = (d > fS[7]) || (d == fS[7] && j < fI[7]);
                if (bt) {
                    fS[7] = d; fI[7] = j;
#pragma unroll
                    for (int q = 7; q > 0; q--) {
                        bool sw = (fS[q] > fS[q - 1]) || (fS[q] == fS[q - 1] && fI[q] < fI[q - 1]);
                        if (sw) {
                            float td = fS[q]; fS[q] = fS[q - 1]; fS[q - 1] = td;
                            int tj = fI[q]; fI[q] = fI[q - 1]; fI[q - 1] = tj;
                        }
                    }
                }
            }
        }
        int nbrs[9];
#pragma unroll
        for (int e = 0; e < 8; e++) nbrs[e] = fI[e];
        nbrs[8] = i;                                   // self-loop
        float adtv[4];
#pragma unroll
        for (int hh = 0; hh < 4; hh++) adtv[hh] = adt[(bN + i) * 4 + hh];
        float mx[4] = { -FLT_MAX, -FLT_MAX, -FLT_MAX, -FLT_MAX };
#pragma unroll
        for (int e = 0; e < 9; e++) {
            long nb = bN + nbrs[e];
#pragma unroll
            for (int hh = 0; hh < 4; hh++) {
                float l = asr[nb * 4 + hh] + adtv[hh];
                l = (l > 0.f) ? l : 0.2f * l;          // leaky_relu 0.2
                mx[hh] = fmaxf(mx[hh], l);
            }
        }
        float sum[4] = { 0, 0, 0, 0 };
        float acc[16];
#pragma unroll
        for (int c = 0; c < 16; c++) acc[c] = 0.f;
#pragma unroll
        for (int e = 0; e < 9; e++) {
            long nb = bN + nbrs[e];
            const float4* xpn = (const float4*)&xp[nb * 16];
            float4 x0 = xpn[0], x1 = xpn[1], x2 = xpn[2], x3 = xpn[3];
            float xv[16] = { x0.x,x0.y,x0.z,x0.w, x1.x,x1.y,x1.z,x1.w,
                             x2.x,x2.y,x2.z,x2.w, x3.x,x3.y,x3.z,x3.w };
            float wv[4];
#pragma unroll
            for (int hh = 0; hh < 4; hh++) {
                float l = asr[nb * 4 + hh] + adtv[hh];
                l = (l > 0.f) ? l : 0.2f * l;
                float w = expf(l - mx[hh]);
                sum[hh] += w; wv[hh] = w;
            }
#pragma unroll
            for (int hh = 0; hh < 4; hh++)
#pragma unroll
                for (int f = 0; f < 4; f++)
                    acc[hh * 4 + f] += wv[hh] * xv[hh * 4 + f];
        }
#pragma unroll
        for (int hh = 0; hh < 4; hh++) {
            float inv = 1.f / sum[hh];
#pragma unroll
            for (int f = 0; f < 4; f++) {
                float o = acc[hh * 4 + f] * inv + bg[hh * 4 + f];
                p[(bN + i) * 16 + hh * 4 + f] = fmaxf(o, 0.f);
            }
        }
    }
}

// ------- 1x1 MLP 16->128->16, fire mask, h += mask*u, 1x1->1 + sigmoid ------
// weights in LDS laid out [hd][16] so each hd reads 8x b128 (Wu2 transposed)
__launch_bounds__(128)
__global__ void k_update(const float* __restrict__ p, const float* __restrict__ h,
                         const float* __restrict__ fire, const float* __restrict__ Wu1,
                         const float* __restrict__ bu1, const float* __restrict__ Wu2,
                         const float* __restrict__ bu2, const float* __restrict__ Wo,
                         const float* __restrict__ bo, float* __restrict__ out_low) {
    __shared__ float sU1[128 * 16];
    __shared__ float sU2t[128 * 16];      // [hd][c] = Wu2[c][hd]
    __shared__ float sb1[128];
    int tid = threadIdx.x;
    for (int k = tid; k < 2048; k += 128) {
        sU1[k] = Wu1[k];
        sU2t[(k & 127) * 16 + (k >> 7)] = Wu2[k];   // coalesced read, scatter to LDS
    }
    sb1[tid] = bu1[tid];
    __syncthreads();
    long n = (long)blockIdx.x * 128 + tid;           // 0..32767
    const float4* pp = (const float4*)&p[n * 16];
    float4 p0 = pp[0], p1 = pp[1], p2 = pp[2], p3 = pp[3];
    float pv[16] = { p0.x,p0.y,p0.z,p0.w, p1.x,p1.y,p1.z,p1.w,
                     p2.x,p2.y,p2.z,p2.w, p3.x,p3.y,p3.z,p3.w };
    float u[16];
#pragma unroll
    for (int c = 0; c < 16; c++) u[c] = bu2[c];
    for (int hd = 0; hd < 128; hd++) {
        const float4* r = (const float4*)&sU1[hd * 16];
        float4 r0 = r[0], r1 = r[1], r2 = r[2], r3 = r[3];
        float a = sb1[hd]
            + r0.x*pv[0] + r0.y*pv[1] + r0.z*pv[2] + r0.w*pv[3]
            + r1.x*pv[4] + r1.y*pv[5] + r1.z*pv[6] + r1.w*pv[7]
            + r2.x*pv[8] + r2.y*pv[9] + r2.z*pv[10]+ r2.w*pv[11]
            + r3.x*pv[12]+ r3.y*pv[13]+ r3.z*pv[14]+ r3.w*pv[15];
        a = fmaxf(a, 0.f);
        const float4* t = (const float4*)&sU2t[hd * 16];
        float4 t0 = t[0], t1 = t[1], t2 = t[2], t3 = t[3];
        u[0] += t0.x*a; u[1] += t0.y*a; u[2] += t0.z*a; u[3] += t0.w*a;
        u[4] += t1.x*a; u[5] += t1.y*a; u[6] += t1.z*a; u[7] += t1.w*a;
        u[8] += t2.x*a; u[9] += t2.y*a; u[10]+= t2.z*a; u[11]+= t2.w*a;
        u[12]+= t3.x*a; u[13]+= t3.y*a; u[14]+= t3.z*a; u[15]+= t3.w*a;
    }
    float mask = (fire[n] < 0.5f) ? 1.f : 0.f;
    const float4* hp = (const float4*)&h[n * 16];
    float4 h0 = hp[0], h1v = hp[1], h2 = hp[2], h3 = hp[3];
    float hv[16] = { h0.x,h0.y,h0.z,h0.w, h1v.x,h1v.y,h1v.z,h1v.w,
                     h2.x,h2.y,h2.z,h2.w, h3.x,h3.y,h3.z,h3.w };
    float o = bo[0];
#pragma unroll
    for (int c = 0; c < 16; c++) o += Wo[c] * (hv[c] + mask * u[c]);
    out_low[n] = 1.f / (1.f + expf(-o));
}

// ---------------- bilinear upsample 64 -> 256 (half-pixel, clamp) -----------
__global__ void k_up(const float* __restrict__ ol, float* __restrict__ out) {
    int t = blockIdx.x * 256 + threadIdx.x;
    if (t >= BATCH * HIGH * HIGH) return;
    int b = t >> 16, oy = (t >> 8) & 255, ox = t & 255;
    float cy = (oy + 0.5f) * 0.25f - 0.5f;
    float cx = (ox + 0.5f) * 0.25f - 0.5f;
    int iy0 = (int)floorf(cy); float fy = cy - (float)iy0;
    int ix0 = (int)floorf(cx); float fx = cx - (float)ix0;
    int y0 = min(max(iy0, 0), 63), y1 = min(max(iy0 + 1, 0), 63);
    int x0 = min(max(ix0, 0), 63), x1 = min(max(ix0 + 1, 0), 63);
    const float* s = ol + b * NN;
    float v = (1.f - fy) * ((1.f - fx) * s[y0 * 64 + x0] + fx * s[y0 * 64 + x1])
            + fy * ((1.f - fx) * s[y1 * 64 + x0] + fx * s[y1 * 64 + x1]);
    out[t] = v;
}

extern "C" void kernel_launch(void* const* d_in, const int* in_sizes, int n_in,
                              void* d_out, int out_size, void* d_ws, size_t ws_size,
                              hipStream_t stream) {
    const float* x    = (const float*)d_in[0];
    const float* fire = (const float*)d_in[1];
    const float* W1   = (const float*)d_in[2];
    const float* b1   = (const float*)d_in[3];
    const float* g1   = (const float*)d_in[4];
    const float* be1  = (const float*)d_in[5];
    const float* m1   = (const float*)d_in[6];
    const float* v1   = (const float*)d_in[7];
    const float* W2   = (const float*)d_in[8];
    const float* b2   = (const float*)d_in[9];
    const float* g2   = (const float*)d_in[10];
    const float* be2  = (const float*)d_in[11];
    const float* m2   = (const float*)d_in[12];
    const float* v2   = (const float*)d_in[13];
    const float* Wg   = (const float*)d_in[14];
    const float* a_src= (const float*)d_in[15];
    const float* a_dst= (const float*)d_in[16];
    const float* bg   = (const float*)d_in[17];
    const float* Wu1  = (const float*)d_in[18];
    const float* bu1  = (const float*)d_in[19];
    const float* Wu2  = (const float*)d_in[20];
    const float* bu2  = (const float*)d_in[21];
    const float* Wo   = (const float*)d_in[22];
    const float* bo   = (const float*)d_in[23];

    float* ws  = (float*)d_ws;
    float* xl  = ws + OFF_XL;
    float* h1  = ws + OFF_H1;
    float* h   = ws + OFF_H;
    float* sq  = ws + OFF_SQ;
    float* xp  = ws + OFF_XP;
    float* asr = ws + OFF_ASR;
    float* adt = ws + OFF_ADT;
    float* p   = ws + OFF_P;
    float* ol  = ws + OFF_OL;

    k_down  <<<(BATCH * NN + 127) / 128, 128, 0, stream>>>(x, xl);
    k_conv1 <<<(BATCH * C1 * NN) / 256, 256, 0, stream>>>(xl, W1, b1, g1, be1, m1, v1, h1);
    k_conv2 <<<BATCH * 32, 128, 0, stream>>>(h1, W2, b2, g2, be2, m2, v2, Wg, a_src, a_dst,
                                             h, sq, xp, asr, adt);
    k_gat   <<<BATCH * 32, 256, 0, stream>>>(h, sq, xp, asr, adt, bg, p);
    k_update<<<BATCH * NN / 128, 128, 0, stream>>>(p, h, fire, Wu1, bu1, Wu2, bu2, Wo, bo, ol);
    k_up    <<<(BATCH * HIGH * HIGH) / 256, 256, 0, stream>>>(ol, (float*)d_out);
}

// Round 4
// 523.782 us; speedup vs baseline: 1.2982x; 1.2982x over previous
//
#include <hip/hip_runtime.h>
#include <math.h>
#include <float.h>

#define BATCH 8
#define HIGH  256
#define LOWR  64
#define NN    4096          // LOWR*LOWR
#define HIDC  16
#define C1    64
#define NSL   4             // j-slices in kNN scan (1024 j each)

// workspace layout (floats) — footprint identical to the validated R1/R2 layout
#define OFF_XL   0
#define OFF_H1   (OFF_XL  + BATCH*NN)            // 2.097M floats; reused for cand after conv2
#define OFF_H    (OFF_H1  + BATCH*C1*NN)         // node-major [B*N][16]
#define OFF_SQ   (OFF_H   + BATCH*NN*HIDC)
#define OFF_XP   (OFF_SQ  + BATCH*NN)
#define OFF_ASR  (OFF_XP  + BATCH*NN*HIDC)
#define OFF_ADT  (OFF_ASR + BATCH*NN*4)
#define OFF_P    (OFF_ADT + BATCH*NN*4)
#define OFF_OL   (OFF_P   + BATCH*NN*HIDC)
// cand_s: BATCH*NSL*NN*8 = 1,048,576 floats at OFF_H1
// cand_i: 1,048,576 ushorts = 524,288 float-slots at OFF_H1 + 1,048,576
// total 1,572,864 < 2,097,152 (h1 region) — no growth past OFF_OL + BATCH*NN.

// ---------------- bilinear downsample 256 -> 64 (antialiased triangle) -------
__global__ void k_down(const float* __restrict__ x, float* __restrict__ xl) {
    int t = blockIdx.x * 128 + threadIdx.x;
    if (t >= BATCH * NN) return;
    int b = t >> 12, oy = (t >> 6) & 63, ox = t & 63;
    const float* xb = x + b * HIGH * HIGH;
    float cy = 4.f * oy + 1.5f, cx = 4.f * ox + 1.5f;
    float wy[8], wx[8], sy = 0.f, sx = 0.f;
#pragma unroll
    for (int k = 0; k < 8; k++) {
        int iy = 4 * oy - 2 + k;
        float w = 1.f - fabsf((float)iy - cy) * 0.25f;
        if (iy < 0 || iy >= HIGH) w = 0.f;
        wy[k] = w; sy += w;
        int ix = 4 * ox - 2 + k;
        float v = 1.f - fabsf((float)ix - cx) * 0.25f;
        if (ix < 0 || ix >= HIGH) v = 0.f;
        wx[k] = v; sx += v;
    }
    float acc = 0.f;
#pragma unroll
    for (int ky = 0; ky < 8; ky++) {
        if (wy[ky] == 0.f) continue;
        int iy = 4 * oy - 2 + ky;
        float rowacc = 0.f;
#pragma unroll
        for (int kx = 0; kx < 8; kx++) {
            if (wx[kx] == 0.f) continue;
            int ix = 4 * ox - 2 + kx;
            rowacc += wx[kx] * xb[iy * HIGH + ix];
        }
        acc += wy[ky] * rowacc;
    }
    xl[t] = acc / (sy * sx);
}

// ---------------- conv3x3 1->64 + BN + relu ---------------------------------
__global__ void k_conv1(const float* __restrict__ xl, const float* __restrict__ W1,
                        const float* __restrict__ b1, const float* __restrict__ g1,
                        const float* __restrict__ be1, const float* __restrict__ m1,
                        const float* __restrict__ v1, float* __restrict__ h1) {
    int t = blockIdx.x * 256 + threadIdx.x;
    if (t >= BATCH * C1 * NN) return;
    int b = t >> 18, co = (t >> 12) & 63, y = (t >> 6) & 63, x = t & 63;
    const float* src = xl + b * NN;
    const float* w = W1 + co * 9;
    float acc = 0.f;
#pragma unroll
    for (int dy = -1; dy <= 1; dy++) {
        int yy = y + dy; if (yy < 0 || yy >= 64) continue;
#pragma unroll
        for (int dx = -1; dx <= 1; dx++) {
            int xx = x + dx; if (xx < 0 || xx >= 64) continue;
            acc += w[(dy + 1) * 3 + (dx + 1)] * src[yy * 64 + xx];
        }
    }
    acc += b1[co];
    float sc = g1[co] / sqrtf(v1[co] + 1e-5f);
    acc = (acc - m1[co]) * sc + be1[co];
    h1[t] = fmaxf(acc, 0.f);
}

// ------- conv3x3 64->16 + BN + relu, fused: h (node-major), sq, xp, asr, adt -
__launch_bounds__(128)
__global__ void k_conv2(const float* __restrict__ h1, const float* __restrict__ W2,
                        const float* __restrict__ b2, const float* __restrict__ g2,
                        const float* __restrict__ be2, const float* __restrict__ m2,
                        const float* __restrict__ v2, const float* __restrict__ Wg,
                        const float* __restrict__ a_src, const float* __restrict__ a_dst,
                        float* __restrict__ h, float* __restrict__ sq,
                        float* __restrict__ xp, float* __restrict__ asr,
                        float* __restrict__ adt) {
    __shared__ float sW2t[576 * 16];    // [ci*9+tap][o]
    __shared__ float sWg[256];
    __shared__ float sA[32];
    int tid = threadIdx.x;
    for (int k = tid; k < 9216; k += 128) {          // coalesced global read, scatter to LDS
        int o = k / 576, ct = k - o * 576;
        sW2t[ct * 16 + o] = W2[k];
    }
    for (int k = tid; k < 256; k += 128) sWg[k] = Wg[k];
    if (tid < 16) { sA[tid] = a_src[tid]; sA[16 + tid] = a_dst[tid]; }
    __syncthreads();
    int blk = blockIdx.x;                 // 8 batches * 32 y-tiles
    int b = blk >> 5, ytile = blk & 31;
    int ty = tid >> 6, x = tid & 63, y = ytile * 2 + ty;
    float acc[16];
#pragma unroll
    for (int o = 0; o < 16; o++) acc[o] = 0.f;
    const float* hb = h1 + (long)b * C1 * NN;
    for (int ci = 0; ci < 64; ci++) {
        const float* plane = hb + ci * NN;
#pragma unroll
        for (int dy = -1; dy <= 1; dy++) {
            int yy = y + dy; bool oky = (yy >= 0 && yy < 64);
#pragma unroll
            for (int dx = -1; dx <= 1; dx++) {
                int xx = x + dx;
                float v = (oky && xx >= 0 && xx < 64) ? plane[yy * 64 + xx] : 0.f;
                int ct = ci * 9 + (dy + 1) * 3 + (dx + 1);
                const float4* wr = (const float4*)&sW2t[ct * 16];
                float4 w0 = wr[0], w1 = wr[1], w2 = wr[2], w3 = wr[3];
                acc[0] += v * w0.x; acc[1] += v * w0.y; acc[2] += v * w0.z; acc[3] += v * w0.w;
                acc[4] += v * w1.x; acc[5] += v * w1.y; acc[6] += v * w1.z; acc[7] += v * w1.w;
                acc[8] += v * w2.x; acc[9] += v * w2.y; acc[10]+= v * w2.z; acc[11]+= v * w2.w;
                acc[12]+= v * w3.x; acc[13]+= v * w3.y; acc[14]+= v * w3.z; acc[15]+= v * w3.w;
            }
        }
    }
    int n = y * 64 + x;
    long node = (long)b * NN + n;
    float nodev[16], sqv = 0.f;
#pragma unroll
    for (int o = 0; o < 16; o++) {
        float a = acc[o] + b2[o];
        float sc = g2[o] / sqrtf(v2[o] + 1e-5f);
        a = (a - m2[o]) * sc + be2[o];
        a = fmaxf(a, 0.f);
        nodev[o] = a; sqv += a * a;
        h[node * 16 + o] = a;
    }
    sq[node] = sqv;
    float xpv[16];
#pragma unroll
    for (int o = 0; o < 16; o++) {
        float a = 0.f;
#pragma unroll
        for (int c = 0; c < 16; c++) a += sWg[o * 16 + c] * nodev[c];
        xpv[o] = a;
        xp[node * 16 + o] = a;
    }
#pragma unroll
    for (int hh = 0; hh < 4; hh++) {
        float as = 0.f, ad = 0.f;
#pragma unroll
        for (int f = 0; f < 4; f++) {
            as += xpv[hh * 4 + f] * sA[hh * 4 + f];
            ad += xpv[hh * 4 + f] * sA[16 + hh * 4 + f];
        }
        asr[node * 4 + hh] = as;
        adt[node * 4 + hh] = ad;
    }
}

// --------- kNN scan: per (row, j-slice) top-8 via wave-uniform j loads ------
// block = 256 threads = 256 rows, all scanning the SAME 1024-j slice in lock-step.
// j-node load is wave-uniform -> scalar/broadcast, no LDS, no barriers.
// grid = 8 batches * 16 rowgroups * 4 slices = 512 blocks (2/CU).
// score = dot(i,j) - 0.5*|j|^2  (monotone-equiv to -dist; strict > + increasing j
// inside a slice keeps lowest-index on ties, matching jax top_k)
__launch_bounds__(256)
__global__ void k_scan(const float* __restrict__ h, const float* __restrict__ sq,
                       float* __restrict__ cand_s, unsigned short* __restrict__ cand_i) {
    int tid = threadIdx.x;
    int blk = blockIdx.x;
    int b  = blk >> 6;
    int rg = (blk >> 2) & 15;
    int sl = blk & 3;
    int i  = rg * 256 + tid;
    long bN = (long)b * NN;
    const float4* ip = (const float4*)&h[(bN + i) * 16];
    float4 r0 = ip[0], r1 = ip[1], r2 = ip[2], r3 = ip[3];
    float ni[16] = { r0.x,r0.y,r0.z,r0.w, r1.x,r1.y,r1.z,r1.w,
                     r2.x,r2.y,r2.z,r2.w, r3.x,r3.y,r3.z,r3.w };
    float s[8]; int id[8];
#pragma unroll
    for (int k = 0; k < 8; k++) { s[k] = -FLT_MAX; id[k] = 65535; }
    int j0 = sl * 1024;
    const float* __restrict__ hj  = h + (bN + j0) * 16;
    const float* __restrict__ sqp = sq + bN + j0;
#pragma unroll 4
    for (int q = 0; q < 1024; q++) {
        const float4* np = (const float4*)(hj + q * 16);
        float4 a0 = np[0], a1 = np[1], a2 = np[2], a3 = np[3];
        float hs = 0.5f * sqp[q];
        float sc = ni[0]*a0.x + ni[1]*a0.y + ni[2]*a0.z + ni[3]*a0.w
                 + ni[4]*a1.x + ni[5]*a1.y + ni[6]*a1.z + ni[7]*a1.w
                 + ni[8]*a2.x + ni[9]*a2.y + ni[10]*a2.z + ni[11]*a2.w
                 + ni[12]*a3.x + ni[13]*a3.y + ni[14]*a3.z + ni[15]*a3.w
                 - hs;
        int j = j0 + q;
        if (sc > s[7] && j != i) {
            s[7] = sc; id[7] = j;
#pragma unroll
            for (int k = 7; k > 0; k--) {
                if (s[k] > s[k - 1]) {
                    float td = s[k]; s[k] = s[k - 1]; s[k - 1] = td;
                    int tj = id[k]; id[k] = id[k - 1]; id[k - 1] = tj;
                }
            }
        }
    }
    long base = ((long)(b * NSL + sl) * NN + i) * 8;
#pragma unroll
    for (int k = 0; k < 8; k++) {
        cand_s[base + k] = s[k];
        cand_i[base + k] = (unsigned short)id[k];
    }
}

// --------- merge 4 per-slice top-8 lists (lex) + GAT epilogue -> p ----------
__launch_bounds__(256)
__global__ void k_gat2(const float* __restrict__ cand_s, const unsigned short* __restrict__ cand_i,
                       const float* __restrict__ xp, const float* __restrict__ asr,
                       const float* __restrict__ adt, const float* __restrict__ bg,
                       float* __restrict__ p) {
    int t = blockIdx.x * 256 + threadIdx.x;       // 0..32767
    int b = t >> 12, i = t & 4095;
    long bN = (long)b * NN;
    float fS[8]; int fI[8];
#pragma unroll
    for (int k = 0; k < 8; k++) { fS[k] = -FLT_MAX; fI[k] = 65535; }
    for (int sl = 0; sl < NSL; sl++) {
        long base = ((long)(b * NSL + sl) * NN + i) * 8;
#pragma unroll
        for (int k = 0; k < 8; k++) {
            float d = cand_s[base + k]; int j = (int)cand_i[base + k];
            bool bt = (d > fS[7]) || (d == fS[7] && j < fI[7]);
            if (bt) {
                fS[7] = d; fI[7] = j;
#pragma unroll
                for (int q = 7; q > 0; q--) {
                    bool sw = (fS[q] > fS[q - 1]) || (fS[q] == fS[q - 1] && fI[q] < fI[q - 1]);
                    if (sw) {
                        float td = fS[q]; fS[q] = fS[q - 1]; fS[q - 1] = td;
                        int tj = fI[q]; fI[q] = fI[q - 1]; fI[q - 1] = tj;
                    }
                }
            }
        }
    }
    int nbrs[9];
#pragma unroll
    for (int e = 0; e < 8; e++) nbrs[e] = fI[e];
    nbrs[8] = i;                                   // self-loop
    float adtv[4];
#pragma unroll
    for (int hh = 0; hh < 4; hh++) adtv[hh] = adt[(bN + i) * 4 + hh];
    float mx[4] = { -FLT_MAX, -FLT_MAX, -FLT_MAX, -FLT_MAX };
    float lg[9][4];
#pragma unroll
    for (int e = 0; e < 9; e++) {
        long nb = bN + nbrs[e];
#pragma unroll
        for (int hh = 0; hh < 4; hh++) {
            float l = asr[nb * 4 + hh] + adtv[hh];
            l = (l > 0.f) ? l : 0.2f * l;          // leaky_relu 0.2
            lg[e][hh] = l;
            mx[hh] = fmaxf(mx[hh], l);
        }
    }
    float sum[4] = { 0, 0, 0, 0 };
    float acc[16];
#pragma unroll
    for (int c = 0; c < 16; c++) acc[c] = 0.f;
#pragma unroll
    for (int e = 0; e < 9; e++) {
        long nb = bN + nbrs[e];
        const float4* xpn = (const float4*)&xp[nb * 16];
        float4 x0 = xpn[0], x1 = xpn[1], x2 = xpn[2], x3 = xpn[3];
        float xv[16] = { x0.x,x0.y,x0.z,x0.w, x1.x,x1.y,x1.z,x1.w,
                         x2.x,x2.y,x2.z,x2.w, x3.x,x3.y,x3.z,x3.w };
        float wv[4];
#pragma unroll
        for (int hh = 0; hh < 4; hh++) {
            float w = expf(lg[e][hh] - mx[hh]);
            sum[hh] += w; wv[hh] = w;
        }
#pragma unroll
        for (int hh = 0; hh < 4; hh++)
#pragma unroll
            for (int f = 0; f < 4; f++)
                acc[hh * 4 + f] += wv[hh] * xv[hh * 4 + f];
    }
#pragma unroll
    for (int hh = 0; hh < 4; hh++) {
        float inv = 1.f / sum[hh];
#pragma unroll
        for (int f = 0; f < 4; f++) {
            float o = acc[hh * 4 + f] * inv + bg[hh * 4 + f];
            p[(bN + i) * 16 + hh * 4 + f] = fmaxf(o, 0.f);
        }
    }
}

// ------- 1x1 MLP 16->128->16, fire mask, h += mask*u, 1x1->1 + sigmoid ------
// hd loop split across 2 thread-halves (2x parallelism), LDS combine.
#define USTR 20
__launch_bounds__(256)
__global__ void k_update(const float* __restrict__ p, const float* __restrict__ h,
                         const float* __restrict__ fire, const float* __restrict__ Wu1,
                         const float* __restrict__ bu1, const float* __restrict__ Wu2,
                         const float* __restrict__ bu2, const float* __restrict__ Wo,
                         const float* __restrict__ bo, float* __restrict__ out_low) {
    __shared__ float sU1[128 * 16];
    __shared__ float sU2t[128 * 16];      // [hd][c] = Wu2[c][hd]
    __shared__ float sb1[128];
    __shared__ float uhalf[128 * USTR];
    int tid = threadIdx.x;
    for (int k = tid; k < 2048; k += 256) {
        sU1[k] = Wu1[k];
        sU2t[(k & 127) * 16 + (k >> 7)] = Wu2[k];   // coalesced read, scatter to LDS
    }
    if (tid < 128) sb1[tid] = bu1[tid];
    __syncthreads();
    int lnode = tid & 127, half = tid >> 7;
    long n = (long)blockIdx.x * 128 + lnode;         // 0..32767
    const float4* pp = (const float4*)&p[n * 16];
    float4 p0 = pp[0], p1 = pp[1], p2 = pp[2], p3 = pp[3];
    float pv[16] = { p0.x,p0.y,p0.z,p0.w, p1.x,p1.y,p1.z,p1.w,
                     p2.x,p2.y,p2.z,p2.w, p3.x,p3.y,p3.z,p3.w };
    float u[16];
#pragma unroll
    for (int c = 0; c < 16; c++) u[c] = 0.f;
    int hd0 = half * 64;
    for (int hd = hd0; hd < hd0 + 64; hd++) {
        const float4* r = (const float4*)&sU1[hd * 16];
        float4 r0 = r[0], r1 = r[1], r2 = r[2], r3 = r[3];
        float a = sb1[hd]
            + r0.x*pv[0] + r0.y*pv[1] + r0.z*pv[2] + r0.w*pv[3]
            + r1.x*pv[4] + r1.y*pv[5] + r1.z*pv[6] + r1.w*pv[7]
            + r2.x*pv[8] + r2.y*pv[9] + r2.z*pv[10]+ r2.w*pv[11]
            + r3.x*pv[12]+ r3.y*pv[13]+ r3.z*pv[14]+ r3.w*pv[15];
        a = fmaxf(a, 0.f);
        const float4* tt = (const float4*)&sU2t[hd * 16];
        float4 t0 = tt[0], t1 = tt[1], t2 = tt[2], t3 = tt[3];
        u[0] += t0.x*a; u[1] += t0.y*a; u[2] += t0.z*a; u[3] += t0.w*a;
        u[4] += t1.x*a; u[5] += t1.y*a; u[6] += t1.z*a; u[7] += t1.w*a;
        u[8] += t2.x*a; u[9] += t2.y*a; u[10]+= t2.z*a; u[11]+= t2.w*a;
        u[12]+= t3.x*a; u[13]+= t3.y*a; u[14]+= t3.z*a; u[15]+= t3.w*a;
    }
    if (half == 1) {
        float4* dst = (float4*)&uhalf[lnode * USTR];
        dst[0] = make_float4(u[0], u[1], u[2], u[3]);
        dst[1] = make_float4(u[4], u[5], u[6], u[7]);
        dst[2] = make_float4(u[8], u[9], u[10], u[11]);
        dst[3] = make_float4(u[12], u[13], u[14], u[15]);
    }
    __syncthreads();
    if (half == 0) {
        const float4* src = (const float4*)&uhalf[lnode * USTR];
        float4 o0 = src[0], o1 = src[1], o2 = src[2], o3 = src[3];
        float ou[16] = { o0.x,o0.y,o0.z,o0.w, o1.x,o1.y,o1.z,o1.w,
                         o2.x,o2.y,o2.z,o2.w, o3.x,o3.y,o3.z,o3.w };
        float mask = (fire[n] < 0.5f) ? 1.f : 0.f;
        const float4* hp = (const float4*)&h[n * 16];
        float4 h0 = hp[0], h1v = hp[1], h2 = hp[2], h3 = hp[3];
        float hv[16] = { h0.x,h0.y,h0.z,h0.w, h1v.x,h1v.y,h1v.z,h1v.w,
                         h2.x,h2.y,h2.z,h2.w, h3.x,h3.y,h3.z,h3.w };
        float o = bo[0];
#pragma unroll
        for (int c = 0; c < 16; c++)
            o += Wo[c] * (hv[c] + mask * (u[c] + ou[c] + bu2[c]));
        out_low[n] = 1.f / (1.f + expf(-o));
    }
}

// ---------------- bilinear upsample 64 -> 256 (half-pixel, clamp) -----------
__global__ void k_up(const float* __restrict__ ol, float* __restrict__ out) {
    int t = blockIdx.x * 256 + threadIdx.x;
    if (t >= BATCH * HIGH * HIGH) return;
    int b = t >> 16, oy = (t >> 8) & 255, ox = t & 255;
    float cy = (oy + 0.5f) * 0.25f - 0.5f;
    float cx = (ox + 0.5f) * 0.25f - 0.5f;
    int iy0 = (int)floorf(cy); float fy = cy - (float)iy0;
    int ix0 = (int)floorf(cx); float fx = cx - (float)ix0;
    int y0 = min(max(iy0, 0), 63), y1 = min(max(iy0 + 1, 0), 63);
    int x0 = min(max(ix0, 0), 63), x1 = min(max(ix0 + 1, 0), 63);
    const float* s = ol + b * NN;
    float v = (1.f - fy) * ((1.f - fx) * s[y0 * 64 + x0] + fx * s[y0 * 64 + x1])
            + fy * ((1.f - fx) * s[y1 * 64 + x0] + fx * s[y1 * 64 + x1]);
    out[t] = v;
}

extern "C" void kernel_launch(void* const* d_in, const int* in_sizes, int n_in,
                              void* d_out, int out_size, void* d_ws, size_t ws_size,
                              hipStream_t stream) {
    const float* x    = (const float*)d_in[0];
    const float* fire = (const float*)d_in[1];
    const float* W1   = (const float*)d_in[2];
    const float* b1   = (const float*)d_in[3];
    const float* g1   = (const float*)d_in[4];
    const float* be1  = (const float*)d_in[5];
    const float* m1   = (const float*)d_in[6];
    const float* v1   = (const float*)d_in[7];
    const float* W2   = (const float*)d_in[8];
    const float* b2   = (const float*)d_in[9];
    const float* g2   = (const float*)d_in[10];
    const float* be2  = (const float*)d_in[11];
    const float* m2   = (const float*)d_in[12];
    const float* v2   = (const float*)d_in[13];
    const float* Wg   = (const float*)d_in[14];
    const float* a_src= (const float*)d_in[15];
    const float* a_dst= (const float*)d_in[16];
    const float* bg   = (const float*)d_in[17];
    const float* Wu1  = (const float*)d_in[18];
    const float* bu1  = (const float*)d_in[19];
    const float* Wu2  = (const float*)d_in[20];
    const float* bu2  = (const float*)d_in[21];
    const float* Wo   = (const float*)d_in[22];
    const float* bo   = (const float*)d_in[23];

    float* ws  = (float*)d_ws;
    float* xl  = ws + OFF_XL;
    float* h1  = ws + OFF_H1;
    float* h   = ws + OFF_H;
    float* sq  = ws + OFF_SQ;
    float* xp  = ws + OFF_XP;
    float* asr = ws + OFF_ASR;
    float* adt = ws + OFF_ADT;
    float* p   = ws + OFF_P;
    float* ol  = ws + OFF_OL;
    float* cand_s = ws + OFF_H1;                              // reuse h1 (dead after conv2)
    unsigned short* cand_i = (unsigned short*)(ws + OFF_H1 + BATCH*NSL*NN*8);

    k_down  <<<(BATCH * NN + 127) / 128, 128, 0, stream>>>(x, xl);
    k_conv1 <<<(BATCH * C1 * NN) / 256, 256, 0, stream>>>(xl, W1, b1, g1, be1, m1, v1, h1);
    k_conv2 <<<BATCH * 32, 128, 0, stream>>>(h1, W2, b2, g2, be2, m2, v2, Wg, a_src, a_dst,
                                             h, sq, xp, asr, adt);
    k_scan  <<<BATCH * 16 * NSL, 256, 0, stream>>>(h, sq, cand_s, cand_i);
    k_gat2  <<<BATCH * NN / 256, 256, 0, stream>>>(cand_s, cand_i, xp, asr, adt, bg, p);
    k_update<<<BATCH * NN / 128, 256, 0, stream>>>(p, h, fire, Wu1, bu1, Wu2, bu2, Wo, bo, ol);
    k_up    <<<(BATCH * HIGH * HIGH) / 256, 256, 0, stream>>>(ol, (float*)d_out);
}

// Round 5
// 437.156 us; speedup vs baseline: 1.5555x; 1.1982x over previous
//
#include <hip/hip_runtime.h>
#include <math.h>
#include <float.h>

#define BATCH 8
#define HIGH  256
#define LOWR  64
#define NN    4096          // LOWR*LOWR
#define HIDC  16
#define C1    64
#define NSL   8             // j-slices in kNN scan (512 j each)

// workspace layout (floats) — footprint identical to the validated R1/R2 layout
#define OFF_XL   0
#define OFF_H1   (OFF_XL  + BATCH*NN)            // 2.097M floats; reused for cand_i after conv2
#define OFF_H    (OFF_H1  + BATCH*C1*NN)         // node-major [B*N][16]
#define OFF_SQ   (OFF_H   + BATCH*NN*HIDC)       // 0.5*|h|^2 per node
#define OFF_XP   (OFF_SQ  + BATCH*NN)
#define OFF_ASR  (OFF_XP  + BATCH*NN*HIDC)
#define OFF_ADT  (OFF_ASR + BATCH*NN*4)
#define OFF_P    (OFF_ADT + BATCH*NN*4)
#define OFF_OL   (OFF_P   + BATCH*NN*HIDC)
// cand_i: BATCH*NSL*NN packed uint4 (8 ushort idx) = 8*8*4096*16 B = 4 MB
//         = 1,048,576 float-slots at OFF_H1 (< 2,097,152) — no footprint growth.

// identical-arithmetic dot used by BOTH k_scan and k_gat2 (bit-equal scores)
__device__ __forceinline__ float dot16m(const float ni[16], float4 a0, float4 a1,
                                        float4 a2, float4 a3, float hs) {
    return ni[0]*a0.x + ni[1]*a0.y + ni[2]*a0.z + ni[3]*a0.w
         + ni[4]*a1.x + ni[5]*a1.y + ni[6]*a1.z + ni[7]*a1.w
         + ni[8]*a2.x + ni[9]*a2.y + ni[10]*a2.z + ni[11]*a2.w
         + ni[12]*a3.x + ni[13]*a3.y + ni[14]*a3.z + ni[15]*a3.w
         - hs;
}

// ---------------- bilinear downsample 256 -> 64 (antialiased triangle) -------
__global__ void k_down(const float* __restrict__ x, float* __restrict__ xl) {
    int t = blockIdx.x * 128 + threadIdx.x;
    if (t >= BATCH * NN) return;
    int b = t >> 12, oy = (t >> 6) & 63, ox = t & 63;
    const float* xb = x + b * HIGH * HIGH;
    float cy = 4.f * oy + 1.5f, cx = 4.f * ox + 1.5f;
    float wy[8], wx[8], sy = 0.f, sx = 0.f;
#pragma unroll
    for (int k = 0; k < 8; k++) {
        int iy = 4 * oy - 2 + k;
        float w = 1.f - fabsf((float)iy - cy) * 0.25f;
        if (iy < 0 || iy >= HIGH) w = 0.f;
        wy[k] = w; sy += w;
        int ix = 4 * ox - 2 + k;
        float v = 1.f - fabsf((float)ix - cx) * 0.25f;
        if (ix < 0 || ix >= HIGH) v = 0.f;
        wx[k] = v; sx += v;
    }
    float acc = 0.f;
#pragma unroll
    for (int ky = 0; ky < 8; ky++) {
        if (wy[ky] == 0.f) continue;
        int iy = 4 * oy - 2 + ky;
        float rowacc = 0.f;
#pragma unroll
        for (int kx = 0; kx < 8; kx++) {
            if (wx[kx] == 0.f) continue;
            int ix = 4 * ox - 2 + kx;
            rowacc += wx[kx] * xb[iy * HIGH + ix];
        }
        acc += wy[ky] * rowacc;
    }
    xl[t] = acc / (sy * sx);
}

// ---------------- conv3x3 1->64 + BN + relu ---------------------------------
__global__ void k_conv1(const float* __restrict__ xl, const float* __restrict__ W1,
                        const float* __restrict__ b1, const float* __restrict__ g1,
                        const float* __restrict__ be1, const float* __restrict__ m1,
                        const float* __restrict__ v1, float* __restrict__ h1) {
    int t = blockIdx.x * 256 + threadIdx.x;
    if (t >= BATCH * C1 * NN) return;
    int b = t >> 18, co = (t >> 12) & 63, y = (t >> 6) & 63, x = t & 63;
    const float* src = xl + b * NN;
    const float* w = W1 + co * 9;
    float acc = 0.f;
#pragma unroll
    for (int dy = -1; dy <= 1; dy++) {
        int yy = y + dy; if (yy < 0 || yy >= 64) continue;
#pragma unroll
        for (int dx = -1; dx <= 1; dx++) {
            int xx = x + dx; if (xx < 0 || xx >= 64) continue;
            acc += w[(dy + 1) * 3 + (dx + 1)] * src[yy * 64 + xx];
        }
    }
    acc += b1[co];
    float sc = g1[co] / sqrtf(v1[co] + 1e-5f);
    acc = (acc - m1[co]) * sc + be1[co];
    h1[t] = fmaxf(acc, 0.f);
}

// ------- conv3x3 64->16 + BN + relu, fused: h (node-major), sq, xp, asr, adt -
__launch_bounds__(128)
__global__ void k_conv2(const float* __restrict__ h1, const float* __restrict__ W2,
                        const float* __restrict__ b2, const float* __restrict__ g2,
                        const float* __restrict__ be2, const float* __restrict__ m2,
                        const float* __restrict__ v2, const float* __restrict__ Wg,
                        const float* __restrict__ a_src, const float* __restrict__ a_dst,
                        float* __restrict__ h, float* __restrict__ sq,
                        float* __restrict__ xp, float* __restrict__ asr,
                        float* __restrict__ adt) {
    __shared__ float sW2t[576 * 16];    // [ci*9+tap][o]
    __shared__ float sWg[256];
    __shared__ float sA[32];
    int tid = threadIdx.x;
    for (int k = tid; k < 9216; k += 128) {          // coalesced global read, scatter to LDS
        int o = k / 576, ct = k - o * 576;
        sW2t[ct * 16 + o] = W2[k];
    }
    for (int k = tid; k < 256; k += 128) sWg[k] = Wg[k];
    if (tid < 16) { sA[tid] = a_src[tid]; sA[16 + tid] = a_dst[tid]; }
    __syncthreads();
    int blk = blockIdx.x;                 // 8 batches * 32 y-tiles
    int b = blk >> 5, ytile = blk & 31;
    int ty = tid >> 6, x = tid & 63, y = ytile * 2 + ty;
    float acc[16];
#pragma unroll
    for (int o = 0; o < 16; o++) acc[o] = 0.f;
    const float* hb = h1 + (long)b * C1 * NN;
    for (int ci = 0; ci < 64; ci++) {
        const float* plane = hb + ci * NN;
#pragma unroll
        for (int dy = -1; dy <= 1; dy++) {
            int yy = y + dy; bool oky = (yy >= 0 && yy < 64);
#pragma unroll
            for (int dx = -1; dx <= 1; dx++) {
                int xx = x + dx;
                float v = (oky && xx >= 0 && xx < 64) ? plane[yy * 64 + xx] : 0.f;
                int ct = ci * 9 + (dy + 1) * 3 + (dx + 1);
                const float4* wr = (const float4*)&sW2t[ct * 16];
                float4 w0 = wr[0], w1 = wr[1], w2 = wr[2], w3 = wr[3];
                acc[0] += v * w0.x; acc[1] += v * w0.y; acc[2] += v * w0.z; acc[3] += v * w0.w;
                acc[4] += v * w1.x; acc[5] += v * w1.y; acc[6] += v * w1.z; acc[7] += v * w1.w;
                acc[8] += v * w2.x; acc[9] += v * w2.y; acc[10]+= v * w2.z; acc[11]+= v * w2.w;
                acc[12]+= v * w3.x; acc[13]+= v * w3.y; acc[14]+= v * w3.z; acc[15]+= v * w3.w;
            }
        }
    }
    int n = y * 64 + x;
    long node = (long)b * NN + n;
    float nodev[16], sqv = 0.f;
#pragma unroll
    for (int o = 0; o < 16; o++) {
        float a = acc[o] + b2[o];
        float sc = g2[o] / sqrtf(v2[o] + 1e-5f);
        a = (a - m2[o]) * sc + be2[o];
        a = fmaxf(a, 0.f);
        nodev[o] = a; sqv += a * a;
        h[node * 16 + o] = a;
    }
    sq[node] = 0.5f * sqv;                // pre-scaled: scan/merge use dot - 0.5|j|^2
    float xpv[16];
#pragma unroll
    for (int o = 0; o < 16; o++) {
        float a = 0.f;
#pragma unroll
        for (int c = 0; c < 16; c++) a += sWg[o * 16 + c] * nodev[c];
        xpv[o] = a;
        xp[node * 16 + o] = a;
    }
#pragma unroll
    for (int hh = 0; hh < 4; hh++) {
        float as = 0.f, ad = 0.f;
#pragma unroll
        for (int f = 0; f < 4; f++) {
            as += xpv[hh * 4 + f] * sA[hh * 4 + f];
            ad += xpv[hh * 4 + f] * sA[16 + hh * 4 + f];
        }
        asr[node * 4 + hh] = as;
        adt[node * 4 + hh] = ad;
    }
}

// --------- kNN scan: per (row, j-slice) top-8, index-only output ------------
// block = 256 threads = 256 rows, all scanning the SAME 512-j slice in lock-step.
// j-node load is wave-uniform -> broadcast, no LDS, no barriers.
// grid = 8 batches * 16 rowgroups * 8 slices = 1024 blocks (4 waves/SIMD).
__launch_bounds__(256)
__global__ void k_scan(const float* __restrict__ h, const float* __restrict__ sq,
                       uint4* __restrict__ cand_i) {
    int tid = threadIdx.x;
    int blk = blockIdx.x;
    int b  = blk >> 7;
    int rg = (blk >> 3) & 15;
    int sl = blk & 7;
    int i  = rg * 256 + tid;
    long bN = (long)b * NN;
    const float4* ip = (const float4*)&h[(bN + i) * 16];
    float4 r0 = ip[0], r1 = ip[1], r2 = ip[2], r3 = ip[3];
    float ni[16] = { r0.x,r0.y,r0.z,r0.w, r1.x,r1.y,r1.z,r1.w,
                     r2.x,r2.y,r2.z,r2.w, r3.x,r3.y,r3.z,r3.w };
    float s[8]; int id[8];
#pragma unroll
    for (int k = 0; k < 8; k++) { s[k] = -FLT_MAX; id[k] = 65535; }
    int j0 = sl * 512;
    const float* __restrict__ hj  = h + (bN + j0) * 16;
    const float* __restrict__ sqp = sq + bN + j0;
#pragma unroll 4
    for (int q = 0; q < 512; q++) {
        const float4* np = (const float4*)(hj + q * 16);
        float4 a0 = np[0], a1 = np[1], a2 = np[2], a3 = np[3];
        float sc = dot16m(ni, a0, a1, a2, a3, sqp[q]);
        int j = j0 + q;
        if (sc > s[7] && j != i) {          // strict > : lowest-index kept on ties
            s[7] = sc; id[7] = j;
#pragma unroll
            for (int k = 7; k > 0; k--) {
                if (s[k] > s[k - 1]) {
                    float td = s[k]; s[k] = s[k - 1]; s[k - 1] = td;
                    int tj = id[k]; id[k] = id[k - 1]; id[k - 1] = tj;
                }
            }
        }
    }
    uint4 pk;
    pk.x = (unsigned)id[0] | ((unsigned)id[1] << 16);
    pk.y = (unsigned)id[2] | ((unsigned)id[3] << 16);
    pk.z = (unsigned)id[4] | ((unsigned)id[5] << 16);
    pk.w = (unsigned)id[6] | ((unsigned)id[7] << 16);
    cand_i[(long)(b * NSL + sl) * NN + i] = pk;
}

// --- merge 8 slice-lists (recompute scores bit-identically) + GAT -> p ------
__launch_bounds__(256)
__global__ void k_gat2(const uint4* __restrict__ cand_i, const float* __restrict__ h,
                       const float* __restrict__ sq,
                       const float* __restrict__ xp, const float* __restrict__ asr,
                       const float* __restrict__ adt, const float* __restrict__ bg,
                       float* __restrict__ p) {
    int t = blockIdx.x * 256 + threadIdx.x;       // 0..32767
    int b = t >> 12, i = t & 4095;
    long bN = (long)b * NN;
    const float4* ip = (const float4*)&h[(bN + i) * 16];
    float4 r0 = ip[0], r1 = ip[1], r2 = ip[2], r3 = ip[3];
    float ni[16] = { r0.x,r0.y,r0.z,r0.w, r1.x,r1.y,r1.z,r1.w,
                     r2.x,r2.y,r2.z,r2.w, r3.x,r3.y,r3.z,r3.w };
    float fS[8]; int fI[8];
#pragma unroll
    for (int k = 0; k < 8; k++) { fS[k] = -FLT_MAX; fI[k] = 65535; }
    for (int sl = 0; sl < NSL; sl++) {
        uint4 pk = cand_i[(long)(b * NSL + sl) * NN + i];
        unsigned idx8[8] = { pk.x & 0xFFFF, pk.x >> 16, pk.y & 0xFFFF, pk.y >> 16,
                             pk.z & 0xFFFF, pk.z >> 16, pk.w & 0xFFFF, pk.w >> 16 };
#pragma unroll
        for (int k = 0; k < 8; k++) {
            int j = (int)idx8[k];
            const float4* np = (const float4*)&h[(bN + j) * 16];
            float4 a0 = np[0], a1 = np[1], a2 = np[2], a3 = np[3];
            float d = dot16m(ni, a0, a1, a2, a3, sq[bN + j]);   // bit-identical to scan
            bool bt = (d > fS[7]) || (d == fS[7] && j < fI[7]);
            if (bt) {
                fS[7] = d; fI[7] = j;
#pragma unroll
                for (int q = 7; q > 0; q--) {
                    bool sw = (fS[q] > fS[q - 1]) || (fS[q] == fS[q - 1] && fI[q] < fI[q - 1]);
                    if (sw) {
                        float td = fS[q]; fS[q] = fS[q - 1]; fS[q - 1] = td;
                        int tj = fI[q]; fI[q] = fI[q - 1]; fI[q - 1] = tj;
                    }
                }
            }
        }
    }
    int nbrs[9];
#pragma unroll
    for (int e = 0; e < 8; e++) nbrs[e] = fI[e];
    nbrs[8] = i;                                   // self-loop
    float adtv[4];
#pragma unroll
    for (int hh = 0; hh < 4; hh++) adtv[hh] = adt[(bN + i) * 4 + hh];
    float mx[4] = { -FLT_MAX, -FLT_MAX, -FLT_MAX, -FLT_MAX };
    float lg[9][4];
#pragma unroll
    for (int e = 0; e < 9; e++) {
        long nb = bN + nbrs[e];
#pragma unroll
        for (int hh = 0; hh < 4; hh++) {
            float l = asr[nb * 4 + hh] + adtv[hh];
            l = (l > 0.f) ? l : 0.2f * l;          // leaky_relu 0.2
            lg[e][hh] = l;
            mx[hh] = fmaxf(mx[hh], l);
        }
    }
    float sum[4] = { 0, 0, 0, 0 };
    float acc[16];
#pragma unroll
    for (int c = 0; c < 16; c++) acc[c] = 0.f;
#pragma unroll
    for (int e = 0; e < 9; e++) {
        long nb = bN + nbrs[e];
        const float4* xpn = (const float4*)&xp[nb * 16];
        float4 x0 = xpn[0], x1 = xpn[1], x2 = xpn[2], x3 = xpn[3];
        float xv[16] = { x0.x,x0.y,x0.z,x0.w, x1.x,x1.y,x1.z,x1.w,
                         x2.x,x2.y,x2.z,x2.w, x3.x,x3.y,x3.z,x3.w };
        float wv[4];
#pragma unroll
        for (int hh = 0; hh < 4; hh++) {
            float w = expf(lg[e][hh] - mx[hh]);
            sum[hh] += w; wv[hh] = w;
        }
#pragma unroll
        for (int hh = 0; hh < 4; hh++)
#pragma unroll
            for (int f = 0; f < 4; f++)
                acc[hh * 4 + f] += wv[hh] * xv[hh * 4 + f];
    }
#pragma unroll
    for (int hh = 0; hh < 4; hh++) {
        float inv = 1.f / sum[hh];
#pragma unroll
        for (int f = 0; f < 4; f++) {
            float o = acc[hh * 4 + f] * inv + bg[hh * 4 + f];
            p[(bN + i) * 16 + hh * 4 + f] = fmaxf(o, 0.f);
        }
    }
}

// ------- 1x1 MLP 16->128->16, fire mask, h += mask*u, 1x1->1 + sigmoid ------
#define USTR 20
__launch_bounds__(256)
__global__ void k_update(const float* __restrict__ p, const float* __restrict__ h,
                         const float* __restrict__ fire, const float* __restrict__ Wu1,
                         const float* __restrict__ bu1, const float* __restrict__ Wu2,
                         const float* __restrict__ bu2, const float* __restrict__ Wo,
                         const float* __restrict__ bo, float* __restrict__ out_low) {
    __shared__ float sU1[128 * 16];
    __shared__ float sU2t[128 * 16];      // [hd][c] = Wu2[c][hd]
    __shared__ float sb1[128];
    __shared__ float uhalf[128 * USTR];
    int tid = threadIdx.x;
    for (int k = tid; k < 2048; k += 256) {
        sU1[k] = Wu1[k];
        sU2t[(k & 127) * 16 + (k >> 7)] = Wu2[k];   // coalesced read, scatter to LDS
    }
    if (tid < 128) sb1[tid] = bu1[tid];
    __syncthreads();
    int lnode = tid & 127, half = tid >> 7;
    long n = (long)blockIdx.x * 128 + lnode;         // 0..32767
    const float4* pp = (const float4*)&p[n * 16];
    float4 p0 = pp[0], p1 = pp[1], p2 = pp[2], p3 = pp[3];
    float pv[16] = { p0.x,p0.y,p0.z,p0.w, p1.x,p1.y,p1.z,p1.w,
                     p2.x,p2.y,p2.z,p2.w, p3.x,p3.y,p3.z,p3.w };
    float u[16];
#pragma unroll
    for (int c = 0; c < 16; c++) u[c] = 0.f;
    int hd0 = half * 64;
    for (int hd = hd0; hd < hd0 + 64; hd++) {
        const float4* r = (const float4*)&sU1[hd * 16];
        float4 r0 = r[0], r1 = r[1], r2 = r[2], r3 = r[3];
        float a = sb1[hd]
            + r0.x*pv[0] + r0.y*pv[1] + r0.z*pv[2] + r0.w*pv[3]
            + r1.x*pv[4] + r1.y*pv[5] + r1.z*pv[6] + r1.w*pv[7]
            + r2.x*pv[8] + r2.y*pv[9] + r2.z*pv[10]+ r2.w*pv[11]
            + r3.x*pv[12]+ r3.y*pv[13]+ r3.z*pv[14]+ r3.w*pv[15];
        a = fmaxf(a, 0.f);
        const float4* tt = (const float4*)&sU2t[hd * 16];
        float4 t0 = tt[0], t1 = tt[1], t2 = tt[2], t3 = tt[3];
        u[0] += t0.x*a; u[1] += t0.y*a; u[2] += t0.z*a; u[3] += t0.w*a;
        u[4] += t1.x*a; u[5] += t1.y*a; u[6] += t1.z*a; u[7] += t1.w*a;
        u[8] += t2.x*a; u[9] += t2.y*a; u[10]+= t2.z*a; u[11]+= t2.w*a;
        u[12]+= t3.x*a; u[13]+= t3.y*a; u[14]+= t3.z*a; u[15]+= t3.w*a;
    }
    if (half == 1) {
        float4* dst = (float4*)&uhalf[lnode * USTR];
        dst[0] = make_float4(u[0], u[1], u[2], u[3]);
        dst[1] = make_float4(u[4], u[5], u[6], u[7]);
        dst[2] = make_float4(u[8], u[9], u[10], u[11]);
        dst[3] = make_float4(u[12], u[13], u[14], u[15]);
    }
    __syncthreads();
    if (half == 0) {
        const float4* src = (const float4*)&uhalf[lnode * USTR];
        float4 o0 = src[0], o1 = src[1], o2 = src[2], o3 = src[3];
        float ou[16] = { o0.x,o0.y,o0.z,o0.w, o1.x,o1.y,o1.z,o1.w,
                         o2.x,o2.y,o2.z,o2.w, o3.x,o3.y,o3.z,o3.w };
        float mask = (fire[n] < 0.5f) ? 1.f : 0.f;
        const float4* hp = (const float4*)&h[n * 16];
        float4 h0 = hp[0], h1v = hp[1], h2 = hp[2], h3 = hp[3];
        float hv[16] = { h0.x,h0.y,h0.z,h0.w, h1v.x,h1v.y,h1v.z,h1v.w,
                         h2.x,h2.y,h2.z,h2.w, h3.x,h3.y,h3.z,h3.w };
        float o = bo[0];
#pragma unroll
        for (int c = 0; c < 16; c++)
            o += Wo[c] * (hv[c] + mask * (u[c] + ou[c] + bu2[c]));
        out_low[n] = 1.f / (1.f + expf(-o));
    }
}

// ---------------- bilinear upsample 64 -> 256 (half-pixel, clamp) -----------
__global__ void k_up(const float* __restrict__ ol, float* __restrict__ out) {
    int t = blockIdx.x * 256 + threadIdx.x;
    if (t >= BATCH * HIGH * HIGH) return;
    int b = t >> 16, oy = (t >> 8) & 255, ox = t & 255;
    float cy = (oy + 0.5f) * 0.25f - 0.5f;
    float cx = (ox + 0.5f) * 0.25f - 0.5f;
    int iy0 = (int)floorf(cy); float fy = cy - (float)iy0;
    int ix0 = (int)floorf(cx); float fx = cx - (float)ix0;
    int y0 = min(max(iy0, 0), 63), y1 = min(max(iy0 + 1, 0), 63);
    int x0 = min(max(ix0, 0), 63), x1 = min(max(ix0 + 1, 0), 63);
    const float* s = ol + b * NN;
    float v = (1.f - fy) * ((1.f - fx) * s[y0 * 64 + x0] + fx * s[y0 * 64 + x1])
            + fy * ((1.f - fx) * s[y1 * 64 + x0] + fx * s[y1 * 64 + x1]);
    out[t] = v;
}

extern "C" void kernel_launch(void* const* d_in, const int* in_sizes, int n_in,
                              void* d_out, int out_size, void* d_ws, size_t ws_size,
                              hipStream_t stream) {
    const float* x    = (const float*)d_in[0];
    const float* fire = (const float*)d_in[1];
    const float* W1   = (const float*)d_in[2];
    const float* b1   = (const float*)d_in[3];
    const float* g1   = (const float*)d_in[4];
    const float* be1  = (const float*)d_in[5];
    const float* m1   = (const float*)d_in[6];
    const float* v1   = (const float*)d_in[7];
    const float* W2   = (const float*)d_in[8];
    const float* b2   = (const float*)d_in[9];
    const float* g2   = (const float*)d_in[10];
    const float* be2  = (const float*)d_in[11];
    const float* m2   = (const float*)d_in[12];
    const float* v2   = (const float*)d_in[13];
    const float* Wg   = (const float*)d_in[14];
    const float* a_src= (const float*)d_in[15];
    const float* a_dst= (const float*)d_in[16];
    const float* bg   = (const float*)d_in[17];
    const float* Wu1  = (const float*)d_in[18];
    const float* bu1  = (const float*)d_in[19];
    const float* Wu2  = (const float*)d_in[20];
    const float* bu2  = (const float*)d_in[21];
    const float* Wo   = (const float*)d_in[22];
    const float* bo   = (const float*)d_in[23];

    float* ws  = (float*)d_ws;
    float* xl  = ws + OFF_XL;
    float* h1  = ws + OFF_H1;
    float* h   = ws + OFF_H;
    float* sq  = ws + OFF_SQ;
    float* xp  = ws + OFF_XP;
    float* asr = ws + OFF_ASR;
    float* adt = ws + OFF_ADT;
    float* p   = ws + OFF_P;
    float* ol  = ws + OFF_OL;
    uint4* cand_i = (uint4*)(ws + OFF_H1);          // reuse h1 (dead after conv2), 4 MB

    k_down  <<<(BATCH * NN + 127) / 128, 128, 0, stream>>>(x, xl);
    k_conv1 <<<(BATCH * C1 * NN) / 256, 256, 0, stream>>>(xl, W1, b1, g1, be1, m1, v1, h1);
    k_conv2 <<<BATCH * 32, 128, 0, stream>>>(h1, W2, b2, g2, be2, m2, v2, Wg, a_src, a_dst,
                                             h, sq, xp, asr, adt);
    k_scan  <<<BATCH * 16 * NSL, 256, 0, stream>>>(h, sq, cand_i);
    k_gat2  <<<BATCH * NN / 256, 256, 0, stream>>>(cand_i, h, sq, xp, asr, adt, bg, p);
    k_update<<<BATCH * NN / 128, 256, 0, stream>>>(p, h, fire, Wu1, bu1, Wu2, bu2, Wo, bo, ol);
    k_up    <<<(BATCH * HIGH * HIGH) / 256, 256, 0, stream>>>(ol, (float*)d_out);
}